// Round 8
// baseline (57478.467 us; speedup 1.0000x reference)
//
#include <hip/hip_runtime.h>
#include <math.h>

#define BIGD 1e10
#define N2C 262144
#define PITCH_AS 257
#define FACF 131328   // floats per packed factor (16 diag packed 528 + 120 full 1024)

typedef double d4 __attribute__((ext_vector_type(4)));

// packed-lower tile offsets (in floats)
__device__ __forceinline__ int tile_off(int bi, int bj) {        // bj < bi, full 1024
    return 512 * bi * (bi - 1) + 528 * bi + (bj << 10);
}
__device__ __forceinline__ int tile_off_diag(int bi) {           // packed lower 528
    return 512 * bi * (bi - 1) + 528 * bi + (bi << 10);
}

// ---------------- block-wide reductions (blockDim = 256) ----------------
__device__ __forceinline__ double blk_reduce_sum_d(double v, double* red) {
    int tid = threadIdx.x;
    red[tid] = v; __syncthreads();
    for (int s = 128; s > 0; s >>= 1) {
        if (tid < s) red[tid] += red[tid + s];
        __syncthreads();
    }
    double r = red[0]; __syncthreads();
    return r;
}
__device__ __forceinline__ double blk_reduce_min_d(double v, double* red) {
    int tid = threadIdx.x;
    red[tid] = v; __syncthreads();
    for (int s = 128; s > 0; s >>= 1) {
        if (tid < s) red[tid] = fmin(red[tid], red[tid + s]);
        __syncthreads();
    }
    double r = red[0]; __syncthreads();
    return r;
}

// ---------------- MFMA-f64 layout self-test (4 candidate D-layouts) ----------------
__device__ __forceinline__ double tAv(int i, int k) { return (double)(1 + i + 17 * k); }
__device__ __forceinline__ double tBv(int k, int j) { return (double)(2 + 3 * j + 31 * k); }

__global__ void k_mfmatest(int* flag) {
    int l = threadIdx.x;                       // 64 threads
    int p = l & 15, q = l >> 4;
    double av = tAv(p, q);                     // A[i=p][k=q]
    double bv = tBv(q, p);                     // B[k=q][j=p]
    d4 c = (d4){0.0, 0.0, 0.0, 0.0};
    c = __builtin_amdgcn_mfma_f64_16x16x4f64(av, bv, c, 0, 0, 0);
    bool okv[4] = {true, true, true, true};
#pragma unroll
    for (int r = 0; r < 4; ++r) {
        int iv[4], jv[4];
        iv[0] = 4 * q + r; jv[0] = p;
        iv[1] = q + 4 * r; jv[1] = p;
        iv[2] = p;         jv[2] = 4 * q + r;
        iv[3] = p;         jv[3] = q + 4 * r;
#pragma unroll
        for (int v = 0; v < 4; ++v) {
            double ref = 0.0;
#pragma unroll
            for (int k = 0; k < 4; ++k) ref += tAv(iv[v], k) * tBv(k, jv[v]);
            okv[v] = okv[v] && (c[r] == ref);
        }
    }
    int sel = 0;
#pragma unroll
    for (int v = 3; v >= 0; --v) {
        unsigned long long m = __ballot(okv[v]);
        if (m == 0xFFFFFFFFFFFFFFFFull) sel = v + 1;
    }
    if (l == 0) flag[0] = sel;
}

// ---------------- elementwise helpers ----------------
__global__ void k_lm(const float* __restrict__ M, const float* __restrict__ L,
                     double* __restrict__ C, int n) {
    int i = blockIdx.x * 256 + threadIdx.x;
    if (i < n) C[i] = (double)M[i] * (double)L[i];
}
__global__ void k_cast(const float* __restrict__ A, double* __restrict__ B, int n) {
    int i = blockIdx.x * 256 + threadIdx.x;
    if (i < n) B[i] = (double)A[i];
}
__global__ void k_cast32v(const double* __restrict__ A, float* __restrict__ B, int n) {
    int i = blockIdx.x * 256 + threadIdx.x;
    if (i < n) B[i] = (float)A[i];
}
__global__ void k_initbsum(double* bsum) {
    if (threadIdx.x == 0) bsum[0] = 1e300;
}

// ---------------- transposes ----------------
__global__ __launch_bounds__(256) void k_transpose_d(const double* __restrict__ A,
                                                     double* __restrict__ B) {
    __shared__ double t[32][33];
    int bx = blockIdx.x & 15, by = blockIdx.x >> 4;
    int x = threadIdx.x & 31, y0 = threadIdx.x >> 5;
#pragma unroll
    for (int l = 0; l < 4; ++l) {
        int y = y0 + 8 * l;
        t[y][x] = A[(size_t)(by * 32 + y) * 512 + bx * 32 + x];
    }
    __syncthreads();
#pragma unroll
    for (int l = 0; l < 4; ++l) {
        int y = y0 + 8 * l;
        B[(size_t)(bx * 32 + y) * 512 + by * 32 + x] = t[x][y];
    }
}
__global__ __launch_bounds__(256) void k_transpose32(const float* __restrict__ A,
                                                     float* __restrict__ B) {
    __shared__ float t[32][33];
    int bx = blockIdx.x & 15, by = blockIdx.x >> 4;
    int x = threadIdx.x & 31, y0 = threadIdx.x >> 5;
#pragma unroll
    for (int l = 0; l < 4; ++l) {
        int y = y0 + 8 * l;
        t[y][x] = A[(size_t)(by * 32 + y) * 512 + bx * 32 + x];
    }
    __syncthreads();
#pragma unroll
    for (int l = 0; l < 4; ++l) {
        int y = y0 + 8 * l;
        B[(size_t)(bx * 32 + y) * 512 + by * 32 + x] = t[x][y];
    }
}

// ---------------- h = s0 + G @ z0 ----------------
__global__ void k_h_d(const float* __restrict__ G, const float* __restrict__ s0,
                      const float* __restrict__ z0, double* __restrict__ h) {
    __shared__ double red[256];
    int tid = threadIdx.x;
    int j = blockIdx.x * 64 + (tid >> 2);
    int q = tid & 3;
    double a = 0.0;
    for (int k = q * 128; k < q * 128 + 128; ++k)
        a += (double)G[(size_t)j * 512 + k] * (double)z0[k];
    red[tid] = a;
    __syncthreads();
    if (q == 0) h[j] = (double)s0[j] + red[tid] + red[tid + 1] + red[tid + 2] + red[tid + 3];
}

// ---------------- fp64 GEMM (precompute): C = sgn*(A1@B1) + diag_eps*I ----------------
__global__ __launch_bounds__(256) void k_bgemm_d(
    const double* __restrict__ A1, const double* __restrict__ B1,
    double* __restrict__ C, double sgn, double diag_eps)
{
    __shared__ double As[32 * 68];
    __shared__ double Bs[32 * 68];
    int bid = blockIdx.x;
    int mt = bid >> 3, nt = bid & 7;
    int m0 = mt * 64, n0 = nt * 64;
    int tid = threadIdx.x;
    int tx = tid & 15, ty = tid >> 4;
    double acc[4][4] = {};
    for (int k0 = 0; k0 < 512; k0 += 32) {
        __syncthreads();
#pragma unroll
        for (int l = 0; l < 8; ++l) {
            int idx = tid + 256 * l;
            int kk = idx & 31, r = idx >> 5;
            As[kk * 68 + r] = A1[(size_t)(m0 + r) * 512 + k0 + kk];
            int cc = idx & 63, k2 = idx >> 6;
            Bs[k2 * 68 + cc] = B1[(size_t)(k0 + k2) * 512 + n0 + cc];
        }
        __syncthreads();
#pragma unroll
        for (int kk = 0; kk < 32; ++kk) {
            double a4[4], b4[4];
#pragma unroll
            for (int u = 0; u < 4; ++u) a4[u] = As[kk * 68 + tx * 4 + u];
#pragma unroll
            for (int u = 0; u < 4; ++u) b4[u] = Bs[kk * 68 + ty * 4 + u];
#pragma unroll
            for (int ii = 0; ii < 4; ++ii)
#pragma unroll
                for (int jj = 0; jj < 4; ++jj)
                    acc[ii][jj] += a4[ii] * b4[jj];
        }
    }
#pragma unroll
    for (int ii = 0; ii < 4; ++ii) {
        int gm = m0 + tx * 4 + ii;
#pragma unroll
        for (int jj = 0; jj < 4; ++jj) {
            int gn = n0 + ty * 4 + jj;
            double v = sgn * acc[ii][jj];
            if (diag_eps != 0.0 && gm == gn) v += diag_eps;
            C[(size_t)gm * 512 + gn] = v;
        }
    }
}

// ---------------- fp32-storage GEMM, fp64 accumulate, 32x64 tile (grid 32) ----------------
__global__ __launch_bounds__(256) void k_gemm32(
    const float* __restrict__ A1, const float* __restrict__ B1,
    const float* __restrict__ A2, const float* __restrict__ B2,
    float* __restrict__ C,
    const float* __restrict__ addp, const float* __restrict__ subp,
    const float* __restrict__ rowp, float rowsgn, float sgn)
{
    __shared__ float As[32 * 36];
    __shared__ float Bs[32 * 68];
    int bid = blockIdx.x;
    int mt = bid >> 3, nt = bid & 7;
    int m0 = mt * 32, n0 = nt * 64;
    int tid = threadIdx.x;
    int tx = tid & 15, ty = tid >> 4;
    double acc[2][4] = {};
    for (int prod = 0; prod < 2; ++prod) {
        const float* A = prod ? A2 : A1;
        const float* B = prod ? B2 : B1;
        if (A == nullptr) break;
        for (int k0 = 0; k0 < 512; k0 += 32) {
            __syncthreads();
#pragma unroll
            for (int l = 0; l < 4; ++l) {
                int idx = tid + 256 * l;
                int kk = idx & 31, r = idx >> 5;
                As[kk * 36 + r] = A[(size_t)(m0 + r) * 512 + k0 + kk];
            }
#pragma unroll
            for (int l = 0; l < 8; ++l) {
                int idx = tid + 256 * l;
                int cc = idx & 63, k2 = idx >> 6;
                Bs[k2 * 68 + cc] = B[(size_t)(k0 + k2) * 512 + n0 + cc];
            }
            __syncthreads();
#pragma unroll
            for (int kk = 0; kk < 32; ++kk) {
                double a2[2], b4[4];
#pragma unroll
                for (int u = 0; u < 2; ++u) a2[u] = (double)As[kk * 36 + tx * 2 + u];
#pragma unroll
                for (int u = 0; u < 4; ++u) b4[u] = (double)Bs[kk * 68 + ty * 4 + u];
#pragma unroll
                for (int ii = 0; ii < 2; ++ii)
#pragma unroll
                    for (int jj = 0; jj < 4; ++jj)
                        acc[ii][jj] += a2[ii] * b4[jj];
            }
        }
    }
#pragma unroll
    for (int ii = 0; ii < 2; ++ii) {
        int gm = m0 + tx * 2 + ii;
#pragma unroll
        for (int jj = 0; jj < 4; ++jj) {
            int gn = n0 + ty * 4 + jj;
            size_t gi = (size_t)gm * 512 + gn;
            double v = (double)sgn * acc[ii][jj];
            if (addp) v += (double)addp[gi];
            if (subp) v -= (double)subp[gi];
            if (rowp) v += (double)rowsgn * (double)rowp[gn];
            C[gi] = (float)v;
        }
    }
}

// ---------------- multi-kernel fp64 blocked Cholesky (precompute) ----------------
__global__ void k_copyadd_d(const double* __restrict__ S, double* __restrict__ F,
                            double dc, int n) {
    int i = blockIdx.x * 256 + threadIdx.x;
    if (i < n) {
        double v = S[i];
        if (dc != 0.0 && (i >> 9) == (i & 511)) v += dc;
        F[i] = v;
    }
}

__global__ __launch_bounds__(512) void k_cpanel_d(double* __restrict__ F, int kp) {
    int c0 = kp * 32, tid = threadIdx.x;
    __shared__ double Dl[32 * 33];
    __shared__ double rdg[32];
    if (tid < 32) {
        int i = tid;
        double d[32];
#pragma unroll
        for (int j = 0; j < 32; ++j) d[j] = F[(size_t)(c0 + i) * 512 + c0 + j];
#pragma unroll
        for (int j = 0; j < 32; ++j) {
            double djj = __shfl(d[j], j);
            djj = (djj > 1e-300) ? djj : 1e-300;
            double sj = sqrt(djj);
            double inv = 1.0 / sj;
            if (i == j) { d[j] = sj; rdg[j] = inv; }
            if (i > j) d[j] *= inv;
            double lij = d[j];
#pragma unroll
            for (int t = j + 1; t < 32; ++t) {
                double ltj = __shfl(d[j], t);
                if (i >= t) d[t] -= lij * ltj;
            }
        }
#pragma unroll
        for (int j = 0; j < 32; ++j) {
            if (j <= i) {
                Dl[i * 33 + j] = d[j];
                F[(size_t)(c0 + i) * 512 + c0 + j] = d[j];
            }
        }
    }
    __syncthreads();
    int r = c0 + 32 + tid;
    if (r < 512) {
        double p[32];
#pragma unroll
        for (int j = 0; j < 32; ++j) p[j] = F[(size_t)r * 512 + c0 + j];
#pragma unroll
        for (int j = 0; j < 32; ++j) {
            double pj = p[j] * rdg[j];
            p[j] = pj;
#pragma unroll
            for (int t = j + 1; t < 32; ++t) p[t] -= pj * Dl[t * 33 + j];
        }
#pragma unroll
        for (int j = 0; j < 32; ++j) F[(size_t)r * 512 + c0 + j] = p[j];
    }
}

__global__ __launch_bounds__(256) void k_syrk_d(double* __restrict__ F, int kp) {
    int c0 = kp * 32;
    int t = blockIdx.x;
    int bi = 0;
    while ((bi + 1) * (bi + 2) / 2 <= t) ++bi;
    int bj = t - bi * (bi + 1) / 2;
    int i0 = c0 + 32 + bi * 64, j0 = c0 + 32 + bj * 64;
    __shared__ double Pa[32 * 68], Pb[32 * 68];
    int tid = threadIdx.x;
#pragma unroll
    for (int l = 0; l < 8; ++l) {
        int idx = tid + 256 * l;
        int kk = idx & 31, r = idx >> 5;
        int ga = i0 + r, gb = j0 + r;
        Pa[kk * 68 + r] = (ga < 512) ? F[(size_t)ga * 512 + c0 + kk] : 0.0;
        Pb[kk * 68 + r] = (gb < 512) ? F[(size_t)gb * 512 + c0 + kk] : 0.0;
    }
    __syncthreads();
    int tx = tid & 15, ty = tid >> 4;
    double acc[4][4] = {};
#pragma unroll
    for (int kk = 0; kk < 32; ++kk) {
        double a4[4], b4[4];
#pragma unroll
        for (int u = 0; u < 4; ++u) a4[u] = Pa[kk * 68 + tx * 4 + u];
#pragma unroll
        for (int u = 0; u < 4; ++u) b4[u] = Pb[kk * 68 + ty * 4 + u];
#pragma unroll
        for (int ii = 0; ii < 4; ++ii)
#pragma unroll
            for (int jj = 0; jj < 4; ++jj)
                acc[ii][jj] += a4[ii] * b4[jj];
    }
#pragma unroll
    for (int ii = 0; ii < 4; ++ii) {
        int gi = i0 + tx * 4 + ii;
        if (gi < 512) {
#pragma unroll
            for (int jj = 0; jj < 4; ++jj) {
                int gj = j0 + ty * 4 + jj;
                if (gj < 512) F[(size_t)gi * 512 + gj] -= acc[ii][jj];
            }
        }
    }
}

// ---------------- fp64 full-square-factor LL^T solve (precompute/init) ----------------
__global__ __launch_bounds__(256) void k_solve_d(
    const double* __restrict__ F,
    const float* __restrict__ rhs32,
    double* __restrict__ o1, double* __restrict__ o2,
    float* __restrict__ o1f, float* __restrict__ o2f,
    int mode)
{
    int b = blockIdx.x;
    int tid = threadIdx.x;
    __shared__ double w[512];
    __shared__ double Ft[64 * 65];
    __shared__ double red[256];
    if (rhs32) {
        w[tid] = (double)rhs32[(size_t)b * 512 + tid];
        w[tid + 256] = (double)rhs32[(size_t)b * 512 + tid + 256];
    } else {
        w[tid] = (tid == b) ? 1.0 : 0.0;
        w[tid + 256] = (tid + 256 == b) ? 1.0 : 0.0;
    }
    for (int blk = 0; blk < 8; ++blk) {
        int c0 = blk * 64;
        int r = tid & 63, q = tid >> 6;
        double acc = 0.0;
        for (int jt = 0; jt < blk; ++jt) {
            __syncthreads();
#pragma unroll
            for (int l = 0; l < 16; ++l) {
                int idx = tid + 256 * l;
                int rr = idx >> 6, cc = idx & 63;
                Ft[rr * 65 + cc] = F[(size_t)(c0 + rr) * 512 + jt * 64 + cc];
            }
            __syncthreads();
#pragma unroll
            for (int jj = 0; jj < 16; ++jj) {
                int j = q * 16 + jj;
                acc += Ft[r * 65 + j] * w[jt * 64 + j];
            }
        }
        red[tid] = acc;
        __syncthreads();
#pragma unroll
        for (int l = 0; l < 16; ++l) {
            int idx = tid + 256 * l;
            int rr = idx >> 6, cc = idx & 63;
            Ft[rr * 65 + cc] = F[(size_t)(c0 + rr) * 512 + c0 + cc];
        }
        __syncthreads();
        if (tid < 64) {
            int i = tid;
            double a = w[c0 + i] - (red[i] + red[i + 64] + red[i + 128] + red[i + 192]);
            double rd = 1.0 / Ft[i * 65 + i];
#pragma unroll
            for (int j = 0; j < 64; ++j) {
                double wj = __shfl(a, j) * __shfl(rd, j);
                if (i == j) w[c0 + i] = wj;
                if (i > j) a -= Ft[i * 65 + j] * wj;
            }
        }
        __syncthreads();
    }
    for (int blk = 7; blk >= 0; --blk) {
        int c0 = blk * 64;
        __syncthreads();
#pragma unroll
        for (int l = 0; l < 16; ++l) {
            int idx = tid + 256 * l;
            int rr = idx >> 6, cc = idx & 63;
            Ft[rr * 65 + cc] = F[(size_t)(c0 + rr) * 512 + c0 + cc];
        }
        __syncthreads();
        if (tid < 64) {
            int i = tid;
            double a = w[c0 + i];
            double rd = 1.0 / Ft[i * 65 + i];
#pragma unroll
            for (int j = 63; j >= 0; --j) {
                double wj = __shfl(a, j) * __shfl(rd, j);
                if (i == j) w[c0 + i] = wj;
                if (i < j) a -= Ft[j * 65 + i] * wj;
            }
        }
        __syncthreads();
        if (c0 > 0) {
            for (int base = 0; base < c0; base += 256) {
                int col = base + tid;
                if (col < c0) {
                    double s = 0.0;
#pragma unroll
                    for (int i2 = 0; i2 < 64; ++i2)
                        s += F[(size_t)(c0 + i2) * 512 + col] * w[c0 + i2];
                    w[col] -= s;
                }
            }
        }
    }
    __syncthreads();
#pragma unroll
    for (int l = 0; l < 2; ++l) {
        int i = tid + l * 256;
        double wv = w[i];
        size_t gi = (size_t)b * 512 + i;
        if (mode == 0) {
            o1[gi] = wv;
            o1f[gi] = (float)wv;
        } else {
            o1[gi] = -wv;
            o2[gi] = wv;
            o1f[gi] = (float)(-wv);
            o2f[gi] = (float)wv;
        }
    }
}

// ---------------- packed fp32-factor triangular solve (512 threads) ----------------
__device__ void trsv_packed(const float* __restrict__ Lb, const double* __restrict__ rdgAll,
                            double* __restrict__ wv, double* __restrict__ red, int tid)
{
    for (int j = 0; j < 16; ++j) {
        int c0 = j * 32;
        int i = tid >> 4, k = tid & 15;
        double a = 0.0;
        if (k < j) {
            const float* tp = Lb + tile_off(j, k) + i * 32;
            const double* wp = wv + k * 32;
#pragma unroll 8
            for (int m = 0; m < 32; ++m) a += (double)tp[m] * wp[m];
        }
        red[tid] = a;
        __syncthreads();
        if (tid < 32) {
            int i2 = tid;
            double s = 0.0;
#pragma unroll
            for (int k2 = 0; k2 < 16; ++k2) s += red[i2 * 16 + k2];
            double aa = wv[c0 + i2] - s;
            double rdgv = rdgAll[c0 + i2];
            const float* tp = Lb + tile_off_diag(j);
            int basei = (i2 * (i2 + 1)) >> 1;
            float lrow[32];
#pragma unroll
            for (int m = 0; m < 32; ++m) lrow[m] = (m < i2) ? tp[basei + m] : 0.f;
#pragma unroll
            for (int m = 0; m < 32; ++m) {
                double xm = __shfl(aa * rdgv, m);
                if (i2 == m) wv[c0 + i2] = xm;
                if (i2 > m) aa -= (double)lrow[m] * xm;
            }
        }
        __syncthreads();
    }
    for (int j = 15; j >= 0; --j) {
        int c0 = j * 32;
        if (tid < 32) {
            int i2 = tid;
            double aa = wv[c0 + i2];
            double rdgv = rdgAll[c0 + i2];
            const float* tp = Lb + tile_off_diag(j);
            float lcol[32];
#pragma unroll
            for (int m = 0; m < 32; ++m)
                lcol[m] = (m > i2) ? tp[((m * (m + 1)) >> 1) + i2] : 0.f;
#pragma unroll
            for (int m = 31; m >= 0; --m) {
                double xm = __shfl(aa * rdgv, m);
                if (i2 == m) wv[c0 + i2] = xm;
                if (i2 < m) aa -= (double)lcol[m] * xm;
            }
        }
        __syncthreads();
        if (j > 0) {
            int k = tid >> 5, m = tid & 31;
            if (k < j) {
                const float* tp = Lb + tile_off(j, k) + m;
                double sacc = 0.0;
#pragma unroll 8
                for (int i3 = 0; i3 < 32; ++i3) sacc += (double)tp[i3 * 32] * wv[c0 + i3];
                wv[k * 32 + m] -= sacc;
            }
            __syncthreads();
        }
    }
}

__device__ void refine_once(const double* __restrict__ S0d, const double* __restrict__ dvecS,
                            const double* __restrict__ rhsL, double* __restrict__ wv,
                            double* __restrict__ tmpS, double* __restrict__ red,
                            const float* __restrict__ Lb, const double* __restrict__ rdgAll,
                            int tid)
{
    double a = 0.0;
    const double* sp = S0d + tid;
    for (int c = 0; c < 512; ++c) a += sp[(size_t)c * 512] * wv[c];
    double r = rhsL[tid] - a - dvecS[tid] * wv[tid];
    __syncthreads();
    tmpS[tid] = r;
    __syncthreads();
    trsv_packed(Lb, rdgAll, tmpS, red, tid);
    wv[tid] += tmpS[tid];
    __syncthreads();
}

// ---------------- persistent fused per-iteration kernel (MFMA-f64 or VALU SYRK) ----------
__global__ __launch_bounds__(512) void k_fused(
    const double* __restrict__ S0d,
    float* __restrict__ F0,
    const double* __restrict__ ss, const double* __restrict__ zs,
    const float* __restrict__ hvf,
    const double* __restrict__ mu, const double* __restrict__ szs,
    float* __restrict__ dzv, float* __restrict__ dsv,
    const int* __restrict__ mfok)
{
    const int tid = threadIdx.x;
    float* Lb = F0 + (size_t)blockIdx.x * FACF;
    const int useM = mfok[0];        // 0 = VALU; 1..4 = MFMA with D-layout variant

    __shared__ double pool[9376];
    __shared__ double Dl[32 * 33];
    __shared__ double rdgS[32];
    __shared__ double rdgAll[512];
    __shared__ double wv[512], rhsL[512], dvecS[512], tmpS[512], redS[512];
    double* As = pool;
    double* Bs = pool + 32 * PITCH_AS;
    double* W  = pool;

    const int tx = tid & 63, ty = tid >> 6;
    const int lane = tid & 63, wid = tid >> 6;
    const int aoff = lane & 15, koff = lane >> 4;

    for (int b = blockIdx.x; b < 128; b += gridDim.x) {
        const size_t gb = (size_t)b * 512;
        __syncthreads();

        // ===== left-looking Cholesky, fp64 arithmetic, packed fp32 store =====
        for (int j = 0; j < 16; ++j) {
            const int c0 = j * 32;
            for (int rbase = c0; rbase < 512; rbase += 256) {
                const int rows = (512 - rbase < 256) ? (512 - rbase) : 256;

                if (useM) {
                    // ---------- MFMA-f64 variant: A direct from global, Bs double-buffered ----
                    const int ntiles = (rows >> 4) << 1;
                    d4 uacc[4];
#pragma unroll
                    for (int tt = 0; tt < 4; ++tt) uacc[tt] = (d4){0.0, 0.0, 0.0, 0.0};
                    if (j > 0) {
                        {   // prologue: stage B tile (j,0) into buffer 0
                            const float* tp = Lb + tile_off(j, 0);
#pragma unroll
                            for (int l = 0; l < 2; ++l) {
                                int idx = tid + 512 * l;
                                int c = idx >> 5, kk = idx & 31;
                                pool[kk * 36 + c] = (double)tp[c * 32 + kk];
                            }
                        }
                        __syncthreads();
                        for (int k = 0; k < j; ++k) {
                            double* Bcur = pool + (k & 1) * 1152;
                            if (k + 1 < j) {   // stage next B tile into other buffer
                                const float* tp = Lb + tile_off(j, k + 1);
                                double* Bnxt = pool + ((k + 1) & 1) * 1152;
#pragma unroll
                                for (int l = 0; l < 2; ++l) {
                                    int idx = tid + 512 * l;
                                    int c = idx >> 5, kk = idx & 31;
                                    Bnxt[kk * 36 + c] = (double)tp[c * 32 + kk];
                                }
                            }
#pragma unroll
                            for (int tt = 0; tt < 4; ++tt) {
                                int t = wid + (tt << 3);
                                if (t < ntiles) {
                                    int s16 = (t >> 1) << 4, hcol = (t & 1) << 4;
                                    int gr = rbase + s16 + aoff;
                                    const float* ap = Lb + tile_off(gr >> 5, k)
                                                      + (gr & 31) * 32 + koff;
                                    d4 uv = uacc[tt];
#pragma unroll
                                    for (int k4 = 0; k4 < 8; ++k4) {
                                        double av = (double)ap[k4 * 4];
                                        double bv = Bcur[(k4 * 4 + koff) * 36 + hcol + aoff];
                                        uv = __builtin_amdgcn_mfma_f64_16x16x4f64(av, bv, uv,
                                                                                  0, 0, 0);
                                    }
                                    uacc[tt] = uv;
                                }
                            }
                            __syncthreads();
                        }
                    }
                    // dump U -> W via the empirically-selected D-layout variant
#pragma unroll
                    for (int tt = 0; tt < 4; ++tt) {
                        int t = wid + (tt << 3);
                        if (t < ntiles) {
                            int s16 = (t >> 1) << 4, hcol = (t & 1) << 4;
#pragma unroll
                            for (int r = 0; r < 4; ++r) {
                                int li, lj;
                                if (useM == 1)      { li = (koff << 2) + r; lj = aoff; }
                                else if (useM == 2) { li = koff + (r << 2); lj = aoff; }
                                else if (useM == 3) { li = aoff; lj = (koff << 2) + r; }
                                else                { li = aoff; lj = koff + (r << 2); }
                                W[(s16 + li) * 33 + hcol + lj] = uacc[tt][r];
                            }
                        }
                    }
                    __syncthreads();
                    // W = S0 (+ s/z diag) - U  (S0 symmetric -> coalesced column reads)
#pragma unroll
                    for (int v = 0; v < 4; ++v) {
                        int cg = c0 + 4 * ty + v;
                        const double* srow = S0d + (size_t)cg * 512 + rbase + tx;
#pragma unroll
                        for (int uu = 0; uu < 4; ++uu) {
                            int rl = tx + 64 * uu;
                            if (rl < rows) {
                                double sv = srow[64 * uu];
                                int rg = rbase + rl;
                                if (rbase == c0 && rg == cg) sv += ss[gb + rg] / zs[gb + rg];
                                W[rl * 33 + 4 * ty + v] = sv - W[rl * 33 + 4 * ty + v];
                            }
                        }
                    }
                } else {
                    // ---------- VALU variant (R4-proven) ----------
                    double acc[4][4];
#pragma unroll
                    for (int v = 0; v < 4; ++v) {
                        int cg = c0 + 4 * ty + v;
                        const double* srow = S0d + (size_t)cg * 512 + rbase + tx;
#pragma unroll
                        for (int u = 0; u < 4; ++u) {
                            int rl = tx + 64 * u;
                            acc[u][v] = (rl < rows) ? srow[64 * u] : 0.0;
                        }
                    }
                    if (rbase == c0) {
#pragma unroll
                        for (int u = 0; u < 4; ++u) {
                            int rg = rbase + tx + 64 * u;
#pragma unroll
                            for (int v = 0; v < 4; ++v) {
                                if (rg == c0 + 4 * ty + v) acc[u][v] += ss[gb + rg] / zs[gb + rg];
                            }
                        }
                    }
                    for (int k = 0; k < j; ++k) {
                        __syncthreads();
                        {
                            int rl0 = tid >> 3;
                            int kq = (tid & 7) * 4;
                            for (int rr = rl0; rr < rows; rr += 64) {
                                int gr = rbase + rr;
                                const float* tp = Lb + tile_off(gr >> 5, k) + (gr & 31) * 32 + kq;
                                float4 f4 = *(const float4*)tp;
                                As[(kq + 0) * PITCH_AS + rr] = (double)f4.x;
                                As[(kq + 1) * PITCH_AS + rr] = (double)f4.y;
                                As[(kq + 2) * PITCH_AS + rr] = (double)f4.z;
                                As[(kq + 3) * PITCH_AS + rr] = (double)f4.w;
                            }
                        }
                        {
                            const float* tp = Lb + tile_off(j, k);
#pragma unroll
                            for (int l = 0; l < 2; ++l) {
                                int idx = tid + 512 * l;
                                int c = idx >> 5, kk = idx & 31;
                                Bs[kk * 36 + c] = (double)tp[c * 32 + kk];
                            }
                        }
                        __syncthreads();
#pragma unroll 8
                        for (int kk = 0; kk < 32; ++kk) {
                            double a4[4], b4[4];
#pragma unroll
                            for (int u = 0; u < 4; ++u) a4[u] = As[kk * PITCH_AS + tx + 64 * u];
#pragma unroll
                            for (int v = 0; v < 4; ++v) b4[v] = Bs[kk * 36 + 4 * ty + v];
#pragma unroll
                            for (int u = 0; u < 4; ++u)
#pragma unroll
                                for (int v = 0; v < 4; ++v)
                                    acc[u][v] -= a4[u] * b4[v];
                        }
                    }
                    __syncthreads();
#pragma unroll
                    for (int u = 0; u < 4; ++u) {
                        int rl = tx + 64 * u;
                        if (rl < rows) {
#pragma unroll
                            for (int v = 0; v < 4; ++v)
                                W[rl * 33 + 4 * ty + v] = acc[u][v];
                        }
                    }
                }
                __syncthreads();

                // ---------- shared: diag factor + panel TRSM + packed fp32 store ----------
                int trsm0 = 0;
                if (rbase == c0) {
                    trsm0 = 32;
                    if (tid < 32) {
                        int i = tid;
                        double d[32];
#pragma unroll
                        for (int m2 = 0; m2 < 32; ++m2) d[m2] = W[i * 33 + m2];
#pragma unroll
                        for (int m2 = 0; m2 < 32; ++m2) {
                            double djj = __shfl(d[m2], m2);
                            djj = (djj > 1e-30) ? djj : 1e-30;
                            double sj = sqrt(djj);
                            double inv = 1.0 / sj;
                            if (i == m2) { d[m2] = sj; rdgS[m2] = inv; rdgAll[c0 + m2] = inv; }
                            if (i > m2) d[m2] *= inv;
                            double lij = d[m2];
#pragma unroll
                            for (int t2 = m2 + 1; t2 < 32; ++t2) {
                                double ltj = __shfl(d[m2], t2);
                                if (i >= t2) d[t2] -= lij * ltj;
                            }
                        }
                        float* tp = Lb + tile_off_diag(j);
                        int basei = (i * (i + 1)) >> 1;
#pragma unroll
                        for (int m2 = 0; m2 < 32; ++m2) {
                            if (m2 <= i) { Dl[i * 33 + m2] = d[m2]; tp[basei + m2] = (float)d[m2]; }
                        }
                    }
                    __syncthreads();
                }
                {
                    int nr = rows - trsm0;
                    if (tid < nr) {
                        int rl = trsm0 + tid;
                        int gr = rbase + rl;
                        double x[32];
#pragma unroll
                        for (int m2 = 0; m2 < 32; ++m2) x[m2] = W[rl * 33 + m2];
#pragma unroll
                        for (int m2 = 0; m2 < 32; ++m2) {
                            double xm = x[m2] * rdgS[m2];
                            x[m2] = xm;
#pragma unroll
                            for (int t2 = m2 + 1; t2 < 32; ++t2) x[t2] -= xm * Dl[t2 * 33 + m2];
                        }
                        float* tp = Lb + tile_off(gr >> 5, j) + (gr & 31) * 32;
#pragma unroll
                        for (int m2 = 0; m2 < 32; ++m2) tp[m2] = (float)x[m2];
                    }
                }
                __syncthreads();
            }
        }

        // ===== affine solve =====
        double z_t = zs[gb + tid], s_t = ss[gb + tid];
        double dv = s_t / z_t;
        dvecS[tid] = dv;
        double r1 = (double)hvf[gb + tid];
        wv[tid] = r1;
        rhsL[tid] = r1;
        __syncthreads();
        trsv_packed(Lb, rdgAll, wv, redS, tid);
        refine_once(S0d, dvecS, rhsL, wv, tmpS, redS, Lb, rdgAll, tid);

        double dza_t = -wv[tid];
        double dsa_t = -(z_t + dza_t) * dv;
        __syncthreads();

        // ===== alpha / sigma / corrector rhs =====
        double az = (dza_t < 0.0) ? (-z_t / dza_t) : BIGD;
        double as = (dsa_t < 0.0) ? (-s_t / dsa_t) : BIGD;
        redS[tid] = fmin(az, as);
        __syncthreads();
        for (int s2 = 256; s2 > 0; s2 >>= 1) {
            if (tid < s2) redS[tid] = fmin(redS[tid], redS[tid + s2]);
            __syncthreads();
        }
        double alpha = fmin(redS[0], 1.0);
        __syncthreads();
        redS[tid] = (s_t + alpha * dsa_t) * (z_t + alpha * dza_t);
        __syncthreads();
        for (int s2 = 256; s2 > 0; s2 >>= 1) {
            if (tid < s2) redS[tid] += redS[tid + s2];
            __syncthreads();
        }
        double d2 = redS[0];
        __syncthreads();
        double ratio = d2 / szs[b];
        double sig = ratio * ratio * ratio;
        double coef = -mu[b] * sig;
        double num = coef + dsa_t * dza_t;
        double rsc_t = num / s_t;
        wv[tid] = num / z_t;
        rhsL[tid] = wv[tid];
        __syncthreads();

        // ===== corrector solve =====
        trsv_packed(Lb, rdgAll, wv, redS, tid);
        refine_once(S0d, dvecS, rhsL, wv, tmpS, redS, Lb, rdgAll, tid);

        double dz = dza_t - wv[tid];
        double ds = -(z_t + rsc_t + dz) * dv;
        dzv[gb + tid] = (float)dz;
        dsv[gb + tid] = (float)ds;
    }
}

// ---------------- per-batch residual stats (fp32 residual inputs) ----------------
__global__ __launch_bounds__(256) void k_stats_d(
    const float* __restrict__ rx, const float* __restrict__ rz,
    const double* __restrict__ ssv, const double* __restrict__ zsv,
    double* resid, double* mu, double* szsum)
{
    int b = blockIdx.x, tid = threadIdx.x;
    __shared__ double red[256];
    double s1 = 0, s2 = 0, s3 = 0;
#pragma unroll
    for (int l = 0; l < 2; ++l) {
        size_t gi = (size_t)b * 512 + tid + l * 256;
        double vx = (double)rx[gi]; s1 += vx * vx;
        double vz = (double)rz[gi]; s2 += vz * vz;
        s3 += ssv[gi] * zsv[gi];
    }
    double t1 = blk_reduce_sum_d(s1, red);
    double t2 = blk_reduce_sum_d(s2, red);
    double t3 = blk_reduce_sum_d(s3, red);
    if (tid == 0) {
        resid[b] = sqrt(t2) + sqrt(t1) + fabs(t3);
        mu[b] = fabs(t3) / 512.0;
        szsum[b] = t3;
    }
}

__global__ void k_best_d(const double* __restrict__ resid, double* bsum, double* flag) {
    __shared__ double red[128];
    int tid = threadIdx.x;
    red[tid] = resid[tid];
    __syncthreads();
    for (int s = 64; s > 0; s >>= 1) {
        if (tid < s) red[tid] += red[tid + s];
        __syncthreads();
    }
    if (tid == 0) {
        double rs = red[0];
        if (rs < bsum[0]) { bsum[0] = rs; flag[0] = 1.0; }
        else flag[0] = 0.0;
    }
}

__global__ void k_bestcopy_d(const double* __restrict__ flag, const double* __restrict__ xs,
                             float* __restrict__ bx) {
    if (flag && flag[0] == 0.0) return;
    int i0 = blockIdx.x * 1024 + threadIdx.x;
#pragma unroll
    for (int l = 0; l < 4; ++l) bx[i0 + l * 256] = (float)xs[i0 + l * 256];
}

// ---------------- final step (fp64 master + fp32 shadows) ----------------
__global__ __launch_bounds__(256) void k_final_d(
    double* __restrict__ xs, double* __restrict__ ssv, double* __restrict__ zsv,
    const float* __restrict__ dxf, const float* __restrict__ dsf, const float* __restrict__ dzf,
    float* __restrict__ xs32, float* __restrict__ ss32, float* __restrict__ zs32)
{
    int b = blockIdx.x, tid = threadIdx.x;
    __shared__ double red[256];
    double m = BIGD;
#pragma unroll
    for (int l = 0; l < 2; ++l) {
        size_t gi = (size_t)b * 512 + tid + l * 256;
        double z = zsv[gi], dz = (double)dzf[gi];
        double az = (dz < 0.0) ? (-z / dz) : BIGD;
        double s = ssv[gi], ds = (double)dsf[gi];
        double as = (ds < 0.0) ? (-s / ds) : BIGD;
        m = fmin(m, fmin(az, as));
    }
    double am = blk_reduce_min_d(m, red);
    double alpha = fmin(0.999 * am, 1.0);
#pragma unroll
    for (int l = 0; l < 2; ++l) {
        size_t gi = (size_t)b * 512 + tid + l * 256;
        double nx = xs[gi] + alpha * (double)dxf[gi];
        double ns = ssv[gi] + alpha * (double)dsf[gi];
        double nz = zsv[gi] + alpha * (double)dzf[gi];
        xs[gi] = nx; ssv[gi] = ns; zsv[gi] = nz;
        xs32[gi] = (float)nx; ss32[gi] = (float)ns; zs32[gi] = (float)nz;
    }
}

// ---------------- initial interior shift (+ shadow refresh) ----------------
__global__ __launch_bounds__(256) void k_shift_d(double* __restrict__ ssv, double* __restrict__ zsv,
                                                 float* __restrict__ ss32, float* __restrict__ zs32)
{
    int b = blockIdx.x, tid = threadIdx.x;
    __shared__ double red[256];
    double m = BIGD;
#pragma unroll
    for (int l = 0; l < 2; ++l) m = fmin(m, ssv[(size_t)b * 512 + tid + l * 256]);
    double smin = blk_reduce_min_d(m, red);
    if (smin < 0.0) {
#pragma unroll
        for (int l = 0; l < 2; ++l) ssv[(size_t)b * 512 + tid + l * 256] += 1.0 - smin;
    }
    m = BIGD;
#pragma unroll
    for (int l = 0; l < 2; ++l) m = fmin(m, zsv[(size_t)b * 512 + tid + l * 256]);
    double zmin = blk_reduce_min_d(m, red);
    if (zmin < 0.0) {
#pragma unroll
        for (int l = 0; l < 2; ++l) zsv[(size_t)b * 512 + tid + l * 256] += 1.0 - zmin;
    }
#pragma unroll
    for (int l = 0; l < 2; ++l) {
        size_t gi = (size_t)b * 512 + tid + l * 256;
        ss32[gi] = (float)ssv[gi];
        zs32[gi] = (float)zsv[gi];
    }
}

extern "C" void kernel_launch(void* const* d_in, const int* in_sizes, int n_in,
                              void* d_out, int out_size, void* d_ws, size_t ws_size,
                              hipStream_t stream)
{
    (void)in_sizes; (void)n_in; (void)out_size;
    const float* xin = (const float*)d_in[0];
    const float* Mi  = (const float*)d_in[1];
    const float* Li  = (const float*)d_in[2];
    const float* Gin = (const float*)d_in[3];
    const float* s0  = (const float*)d_in[4];
    const float* z0  = (const float*)d_in[5];
    float* outp = (float*)d_out;

    const size_t N2 = N2C;
    double* base = (double*)d_ws;
    size_t off = 0;
    auto A = [&](size_t n) { double* p = base + off; off += n; return p; };
    // persistent fp64
    double* S0d  = A(N2);
    double* h    = A(512);
    double* resid = A(128); double* mu = A(128); double* szs = A(128);
    double* bsum = A(8); double* flag = A(8);
    double* mfokd = A(8);
    int* mfok = (int*)mfokd;
    double* xs = A(65536); double* ss = A(65536); double* zs = A(65536);
    // persistent fp32 (allocated in dbl units)
    float* Qf   = (float*)A(131072);
    float* GTf  = (float*)A(131072);
    float* Qif  = (float*)A(131072);
    float* h32  = (float*)A(256);
    float* rxf  = (float*)A(32768);
    float* rzf  = (float*)A(32768);
    float* hvf  = (float*)A(32768);
    float* t1f  = (float*)A(32768);
    float* dzvf = (float*)A(32768);
    float* dsvf = (float*)A(32768);
    float* xs32 = (float*)A(32768);
    float* ss32 = (float*)A(32768);
    float* zs32 = (float*)A(32768);
    float* dxf = hvf;   // alias: hv dead after fused
    float* t2f = t1f;   // alias: t1 dead after hv GEMM

    double* slab = base + off;
    size_t avail = (ws_size / 8 > off) ? (ws_size / 8 - off) : 0;
    int C = (int)(avail / (FACF / 2));   // FACF floats = FACF/2 dbl per batch
    if (C > 128) C = 128;
    if (C < 1) C = 1;
    float* F0 = (float*)slab;
    // precompute fp64 overlays in slab (dead once iterations start)
    double* Lm64  = slab;
    double* LmT64 = slab + 1 * N2;
    double* Q64   = slab + 2 * N2;
    double* Lq    = slab + 3 * N2;
    double* Qi64  = slab + 4 * N2;
    double* G64   = slab + 5 * N2;
    double* GT64  = slab + 6 * N2;
    double* X64   = slab + 7 * N2;
    double* SfI   = slab + 8 * N2;

    dim3 t256(256), t512(512);
    const float* NPf = nullptr;

    // -------- precompute --------
    k_mfmatest<<<1, 64, 0, stream>>>(mfok);
    k_lm<<<1024, t256, 0, stream>>>(Mi, Li, Lm64, 262144);
    k_transpose_d<<<256, t256, 0, stream>>>(Lm64, LmT64);
    k_bgemm_d<<<64, t256, 0, stream>>>(Lm64, LmT64, Q64, 1.0, 1e-4);
    k_cast32v<<<1024, t256, 0, stream>>>(Q64, Qf, 262144);
    k_copyadd_d<<<1024, t256, 0, stream>>>(Q64, Lq, 0.0, 262144);
    for (int kp = 0; kp < 16; ++kp) {
        k_cpanel_d<<<1, t512, 0, stream>>>(Lq, kp);
        int Tr = 480 - 32 * kp;
        if (Tr > 0) {
            int T = (Tr + 63) >> 6;
            k_syrk_d<<<T * (T + 1) / 2, t256, 0, stream>>>(Lq, kp);
        }
    }
    k_solve_d<<<512, t256, 0, stream>>>(Lq, NPf, Qi64, nullptr, Qif, nullptr, 0);
    k_cast<<<1024, t256, 0, stream>>>(Gin, G64, 262144);
    k_transpose_d<<<256, t256, 0, stream>>>(G64, GT64);
    k_transpose32<<<256, t256, 0, stream>>>(Gin, GTf);
    k_bgemm_d<<<64, t256, 0, stream>>>(Qi64, GT64, X64, 1.0, 0.0);
    k_bgemm_d<<<64, t256, 0, stream>>>(G64, X64, S0d, 1.0, 0.0);
    k_copyadd_d<<<1024, t256, 0, stream>>>(S0d, SfI, 1.0, 262144);
    for (int kp = 0; kp < 16; ++kp) {
        k_cpanel_d<<<1, t512, 0, stream>>>(SfI, kp);
        int Tr = 480 - 32 * kp;
        if (Tr > 0) {
            int T = (Tr + 63) >> 6;
            k_syrk_d<<<T * (T + 1) / 2, t256, 0, stream>>>(SfI, kp);
        }
    }
    k_h_d<<<8, t256, 0, stream>>>(Gin, s0, z0, h);
    k_cast32v<<<2, t256, 0, stream>>>(h, h32, 512);
    k_initbsum<<<1, 64, 0, stream>>>(bsum);

    // -------- initial point --------
    k_gemm32<<<32, t256, 0, stream>>>(xin, Qif, NPf, NPf, t1f, NPf, NPf, NPf, 0.f, 1.f);
    k_gemm32<<<32, t256, 0, stream>>>(t1f, GTf, NPf, NPf, hvf, NPf, NPf, h32, 1.f, 1.f);
    k_solve_d<<<128, t256, 0, stream>>>(SfI, hvf, zs, ss, zs32, ss32, 1);
    k_gemm32<<<32, t256, 0, stream>>>(zs32, Gin, NPf, NPf, t1f, xin, NPf, NPf, 0.f, 1.f);
    k_gemm32<<<32, t256, 0, stream>>>(t1f, Qif, NPf, NPf, xs32, NPf, NPf, NPf, 0.f, -1.f);
    k_cast<<<256, t256, 0, stream>>>(xs32, xs, 65536);
    k_shift_d<<<128, t256, 0, stream>>>(ss, zs, ss32, zs32);
    k_bestcopy_d<<<64, t256, 0, stream>>>(nullptr, xs, outp);

    // -------- 20 PDIPM iterations --------
    int fgrid = (C < 128) ? C : 128;
    for (int it = 0; it < 20; ++it) {
        k_gemm32<<<32, t256, 0, stream>>>(xs32, Qf, zs32, Gin, rxf, xin, NPf, NPf, 0.f, 1.f);
        k_gemm32<<<32, t256, 0, stream>>>(xs32, GTf, NPf, NPf, rzf, ss32, NPf, h32, -1.f, 1.f);
        k_stats_d<<<128, t256, 0, stream>>>(rxf, rzf, ss, zs, resid, mu, szs);
        k_best_d<<<1, 128, 0, stream>>>(resid, bsum, flag);
        k_bestcopy_d<<<64, t256, 0, stream>>>(flag, xs, outp);
        k_gemm32<<<32, t256, 0, stream>>>(rxf, Qif, NPf, NPf, t1f, NPf, NPf, NPf, 0.f, 1.f);
        k_gemm32<<<32, t256, 0, stream>>>(t1f, GTf, NPf, NPf, hvf, ss32, rzf, NPf, 0.f, 1.f);
        k_fused<<<fgrid, t512, 0, stream>>>(S0d, F0, ss, zs, hvf, mu, szs, dzvf, dsvf, mfok);
        k_gemm32<<<32, t256, 0, stream>>>(dzvf, Gin, NPf, NPf, t2f, rxf, NPf, NPf, 0.f, 1.f);
        k_gemm32<<<32, t256, 0, stream>>>(t2f, Qif, NPf, NPf, dxf, NPf, NPf, NPf, 0.f, -1.f);
        k_final_d<<<128, t256, 0, stream>>>(xs, ss, zs, dxf, dsvf, dzvf, xs32, ss32, zs32);
    }
}

// Round 9
// 50303.867 us; speedup vs baseline: 1.1426x; 1.1426x over previous
//
#include <hip/hip_runtime.h>
#include <math.h>

#define BIGD 1e10
#define N2C 262144
#define PITCH_AS 257
#define FACF 131328   // floats per packed factor (16 diag packed 528 + 120 full 1024)

typedef double d4 __attribute__((ext_vector_type(4)));

// packed-lower tile offsets (in floats)
__device__ __forceinline__ int tile_off(int bi, int bj) {        // bj < bi, full 1024
    return 512 * bi * (bi - 1) + 528 * bi + (bj << 10);
}
__device__ __forceinline__ int tile_off_diag(int bi) {           // packed lower 528
    return 512 * bi * (bi - 1) + 528 * bi + (bi << 10);
}

// ---------------- block-wide reductions (blockDim = 256) ----------------
__device__ __forceinline__ double blk_reduce_sum_d(double v, double* red) {
    int tid = threadIdx.x;
    red[tid] = v; __syncthreads();
    for (int s = 128; s > 0; s >>= 1) {
        if (tid < s) red[tid] += red[tid + s];
        __syncthreads();
    }
    double r = red[0]; __syncthreads();
    return r;
}
__device__ __forceinline__ double blk_reduce_min_d(double v, double* red) {
    int tid = threadIdx.x;
    red[tid] = v; __syncthreads();
    for (int s = 128; s > 0; s >>= 1) {
        if (tid < s) red[tid] = fmin(red[tid], red[tid + s]);
        __syncthreads();
    }
    double r = red[0]; __syncthreads();
    return r;
}

// ---------------- MFMA-f64 layout self-test (4 candidate D-layouts) ----------------
__device__ __forceinline__ double tAv(int i, int k) { return (double)(1 + i + 17 * k); }
__device__ __forceinline__ double tBv(int k, int j) { return (double)(2 + 3 * j + 31 * k); }

__global__ void k_mfmatest(int* flag) {
    int l = threadIdx.x;                       // 64 threads
    int p = l & 15, q = l >> 4;
    double av = tAv(p, q);                     // A[i=p][k=q]
    double bv = tBv(q, p);                     // B[k=q][j=p]
    d4 c = (d4){0.0, 0.0, 0.0, 0.0};
    c = __builtin_amdgcn_mfma_f64_16x16x4f64(av, bv, c, 0, 0, 0);
    bool okv[4] = {true, true, true, true};
#pragma unroll
    for (int r = 0; r < 4; ++r) {
        int iv[4], jv[4];
        iv[0] = 4 * q + r; jv[0] = p;
        iv[1] = q + 4 * r; jv[1] = p;
        iv[2] = p;         jv[2] = 4 * q + r;
        iv[3] = p;         jv[3] = q + 4 * r;
#pragma unroll
        for (int v = 0; v < 4; ++v) {
            double ref = 0.0;
#pragma unroll
            for (int k = 0; k < 4; ++k) ref += tAv(iv[v], k) * tBv(k, jv[v]);
            okv[v] = okv[v] && (c[r] == ref);
        }
    }
    int sel = 0;
#pragma unroll
    for (int v = 3; v >= 0; --v) {
        unsigned long long m = __ballot(okv[v]);
        if (m == 0xFFFFFFFFFFFFFFFFull) sel = v + 1;
    }
    if (l == 0) flag[0] = sel;
}

// ---------------- elementwise helpers ----------------
__global__ void k_lm(const float* __restrict__ M, const float* __restrict__ L,
                     double* __restrict__ C, int n) {
    int i = blockIdx.x * 256 + threadIdx.x;
    if (i < n) C[i] = (double)M[i] * (double)L[i];
}
__global__ void k_cast(const float* __restrict__ A, double* __restrict__ B, int n) {
    int i = blockIdx.x * 256 + threadIdx.x;
    if (i < n) B[i] = (double)A[i];
}
__global__ void k_cast32v(const double* __restrict__ A, float* __restrict__ B, int n) {
    int i = blockIdx.x * 256 + threadIdx.x;
    if (i < n) B[i] = (float)A[i];
}
__global__ void k_initbsum(double* bsum) {
    if (threadIdx.x == 0) bsum[0] = 1e300;
}

// ---------------- transposes ----------------
__global__ __launch_bounds__(256) void k_transpose_d(const double* __restrict__ A,
                                                     double* __restrict__ B) {
    __shared__ double t[32][33];
    int bx = blockIdx.x & 15, by = blockIdx.x >> 4;
    int x = threadIdx.x & 31, y0 = threadIdx.x >> 5;
#pragma unroll
    for (int l = 0; l < 4; ++l) {
        int y = y0 + 8 * l;
        t[y][x] = A[(size_t)(by * 32 + y) * 512 + bx * 32 + x];
    }
    __syncthreads();
#pragma unroll
    for (int l = 0; l < 4; ++l) {
        int y = y0 + 8 * l;
        B[(size_t)(bx * 32 + y) * 512 + by * 32 + x] = t[x][y];
    }
}
__global__ __launch_bounds__(256) void k_transpose32(const float* __restrict__ A,
                                                     float* __restrict__ B) {
    __shared__ float t[32][33];
    int bx = blockIdx.x & 15, by = blockIdx.x >> 4;
    int x = threadIdx.x & 31, y0 = threadIdx.x >> 5;
#pragma unroll
    for (int l = 0; l < 4; ++l) {
        int y = y0 + 8 * l;
        t[y][x] = A[(size_t)(by * 32 + y) * 512 + bx * 32 + x];
    }
    __syncthreads();
#pragma unroll
    for (int l = 0; l < 4; ++l) {
        int y = y0 + 8 * l;
        B[(size_t)(bx * 32 + y) * 512 + by * 32 + x] = t[x][y];
    }
}

// ---------------- h = s0 + G @ z0 ----------------
__global__ void k_h_d(const float* __restrict__ G, const float* __restrict__ s0,
                      const float* __restrict__ z0, double* __restrict__ h) {
    __shared__ double red[256];
    int tid = threadIdx.x;
    int j = blockIdx.x * 64 + (tid >> 2);
    int q = tid & 3;
    double a = 0.0;
    for (int k = q * 128; k < q * 128 + 128; ++k)
        a += (double)G[(size_t)j * 512 + k] * (double)z0[k];
    red[tid] = a;
    __syncthreads();
    if (q == 0) h[j] = (double)s0[j] + red[tid] + red[tid + 1] + red[tid + 2] + red[tid + 3];
}

// ---------------- fp64 GEMM (precompute): C = sgn*(A1@B1) + diag_eps*I ----------------
__global__ __launch_bounds__(256) void k_bgemm_d(
    const double* __restrict__ A1, const double* __restrict__ B1,
    double* __restrict__ C, double sgn, double diag_eps)
{
    __shared__ double As[32 * 68];
    __shared__ double Bs[32 * 68];
    int bid = blockIdx.x;
    int mt = bid >> 3, nt = bid & 7;
    int m0 = mt * 64, n0 = nt * 64;
    int tid = threadIdx.x;
    int tx = tid & 15, ty = tid >> 4;
    double acc[4][4] = {};
    for (int k0 = 0; k0 < 512; k0 += 32) {
        __syncthreads();
#pragma unroll
        for (int l = 0; l < 8; ++l) {
            int idx = tid + 256 * l;
            int kk = idx & 31, r = idx >> 5;
            As[kk * 68 + r] = A1[(size_t)(m0 + r) * 512 + k0 + kk];
            int cc = idx & 63, k2 = idx >> 6;
            Bs[k2 * 68 + cc] = B1[(size_t)(k0 + k2) * 512 + n0 + cc];
        }
        __syncthreads();
#pragma unroll
        for (int kk = 0; kk < 32; ++kk) {
            double a4[4], b4[4];
#pragma unroll
            for (int u = 0; u < 4; ++u) a4[u] = As[kk * 68 + tx * 4 + u];
#pragma unroll
            for (int u = 0; u < 4; ++u) b4[u] = Bs[kk * 68 + ty * 4 + u];
#pragma unroll
            for (int ii = 0; ii < 4; ++ii)
#pragma unroll
                for (int jj = 0; jj < 4; ++jj)
                    acc[ii][jj] += a4[ii] * b4[jj];
        }
    }
#pragma unroll
    for (int ii = 0; ii < 4; ++ii) {
        int gm = m0 + tx * 4 + ii;
#pragma unroll
        for (int jj = 0; jj < 4; ++jj) {
            int gn = n0 + ty * 4 + jj;
            double v = sgn * acc[ii][jj];
            if (diag_eps != 0.0 && gm == gn) v += diag_eps;
            C[(size_t)gm * 512 + gn] = v;
        }
    }
}

// ---------------- fp32-storage GEMM, fp64 accumulate, 32x64 tile (grid 32) ----------------
__global__ __launch_bounds__(256) void k_gemm32(
    const float* __restrict__ A1, const float* __restrict__ B1,
    const float* __restrict__ A2, const float* __restrict__ B2,
    float* __restrict__ C,
    const float* __restrict__ addp, const float* __restrict__ subp,
    const float* __restrict__ rowp, float rowsgn, float sgn)
{
    __shared__ float As[32 * 36];
    __shared__ float Bs[32 * 68];
    int bid = blockIdx.x;
    int mt = bid >> 3, nt = bid & 7;
    int m0 = mt * 32, n0 = nt * 64;
    int tid = threadIdx.x;
    int tx = tid & 15, ty = tid >> 4;
    double acc[2][4] = {};
    for (int prod = 0; prod < 2; ++prod) {
        const float* A = prod ? A2 : A1;
        const float* B = prod ? B2 : B1;
        if (A == nullptr) break;
        for (int k0 = 0; k0 < 512; k0 += 32) {
            __syncthreads();
#pragma unroll
            for (int l = 0; l < 4; ++l) {
                int idx = tid + 256 * l;
                int kk = idx & 31, r = idx >> 5;
                As[kk * 36 + r] = A[(size_t)(m0 + r) * 512 + k0 + kk];
            }
#pragma unroll
            for (int l = 0; l < 8; ++l) {
                int idx = tid + 256 * l;
                int cc = idx & 63, k2 = idx >> 6;
                Bs[k2 * 68 + cc] = B[(size_t)(k0 + k2) * 512 + n0 + cc];
            }
            __syncthreads();
#pragma unroll
            for (int kk = 0; kk < 32; ++kk) {
                double a2[2], b4[4];
#pragma unroll
                for (int u = 0; u < 2; ++u) a2[u] = (double)As[kk * 36 + tx * 2 + u];
#pragma unroll
                for (int u = 0; u < 4; ++u) b4[u] = (double)Bs[kk * 68 + ty * 4 + u];
#pragma unroll
                for (int ii = 0; ii < 2; ++ii)
#pragma unroll
                    for (int jj = 0; jj < 4; ++jj)
                        acc[ii][jj] += a2[ii] * b4[jj];
            }
        }
    }
#pragma unroll
    for (int ii = 0; ii < 2; ++ii) {
        int gm = m0 + tx * 2 + ii;
#pragma unroll
        for (int jj = 0; jj < 4; ++jj) {
            int gn = n0 + ty * 4 + jj;
            size_t gi = (size_t)gm * 512 + gn;
            double v = (double)sgn * acc[ii][jj];
            if (addp) v += (double)addp[gi];
            if (subp) v -= (double)subp[gi];
            if (rowp) v += (double)rowsgn * (double)rowp[gn];
            C[gi] = (float)v;
        }
    }
}

// ---------------- multi-kernel fp64 blocked Cholesky (precompute) ----------------
__global__ void k_copyadd_d(const double* __restrict__ S, double* __restrict__ F,
                            double dc, int n) {
    int i = blockIdx.x * 256 + threadIdx.x;
    if (i < n) {
        double v = S[i];
        if (dc != 0.0 && (i >> 9) == (i & 511)) v += dc;
        F[i] = v;
    }
}

__global__ __launch_bounds__(512) void k_cpanel_d(double* __restrict__ F, int kp) {
    int c0 = kp * 32, tid = threadIdx.x;
    __shared__ double Dl[32 * 33];
    __shared__ double rdg[32];
    if (tid < 32) {
        int i = tid;
        double d[32];
#pragma unroll
        for (int j = 0; j < 32; ++j) d[j] = F[(size_t)(c0 + i) * 512 + c0 + j];
#pragma unroll
        for (int j = 0; j < 32; ++j) {
            double djj = __shfl(d[j], j);
            djj = (djj > 1e-300) ? djj : 1e-300;
            double sj = sqrt(djj);
            double inv = 1.0 / sj;
            if (i == j) { d[j] = sj; rdg[j] = inv; }
            if (i > j) d[j] *= inv;
            double lij = d[j];
#pragma unroll
            for (int t = j + 1; t < 32; ++t) {
                double ltj = __shfl(d[j], t);
                if (i >= t) d[t] -= lij * ltj;
            }
        }
#pragma unroll
        for (int j = 0; j < 32; ++j) {
            if (j <= i) {
                Dl[i * 33 + j] = d[j];
                F[(size_t)(c0 + i) * 512 + c0 + j] = d[j];
            }
        }
    }
    __syncthreads();
    int r = c0 + 32 + tid;
    if (r < 512) {
        double p[32];
#pragma unroll
        for (int j = 0; j < 32; ++j) p[j] = F[(size_t)r * 512 + c0 + j];
#pragma unroll
        for (int j = 0; j < 32; ++j) {
            double pj = p[j] * rdg[j];
            p[j] = pj;
#pragma unroll
            for (int t = j + 1; t < 32; ++t) p[t] -= pj * Dl[t * 33 + j];
        }
#pragma unroll
        for (int j = 0; j < 32; ++j) F[(size_t)r * 512 + c0 + j] = p[j];
    }
}

__global__ __launch_bounds__(256) void k_syrk_d(double* __restrict__ F, int kp) {
    int c0 = kp * 32;
    int t = blockIdx.x;
    int bi = 0;
    while ((bi + 1) * (bi + 2) / 2 <= t) ++bi;
    int bj = t - bi * (bi + 1) / 2;
    int i0 = c0 + 32 + bi * 64, j0 = c0 + 32 + bj * 64;
    __shared__ double Pa[32 * 68], Pb[32 * 68];
    int tid = threadIdx.x;
#pragma unroll
    for (int l = 0; l < 8; ++l) {
        int idx = tid + 256 * l;
        int kk = idx & 31, r = idx >> 5;
        int ga = i0 + r, gb = j0 + r;
        Pa[kk * 68 + r] = (ga < 512) ? F[(size_t)ga * 512 + c0 + kk] : 0.0;
        Pb[kk * 68 + r] = (gb < 512) ? F[(size_t)gb * 512 + c0 + kk] : 0.0;
    }
    __syncthreads();
    int tx = tid & 15, ty = tid >> 4;
    double acc[4][4] = {};
#pragma unroll
    for (int kk = 0; kk < 32; ++kk) {
        double a4[4], b4[4];
#pragma unroll
        for (int u = 0; u < 4; ++u) a4[u] = Pa[kk * 68 + tx * 4 + u];
#pragma unroll
        for (int u = 0; u < 4; ++u) b4[u] = Pb[kk * 68 + ty * 4 + u];
#pragma unroll
        for (int ii = 0; ii < 4; ++ii)
#pragma unroll
            for (int jj = 0; jj < 4; ++jj)
                acc[ii][jj] += a4[ii] * b4[jj];
    }
#pragma unroll
    for (int ii = 0; ii < 4; ++ii) {
        int gi = i0 + tx * 4 + ii;
        if (gi < 512) {
#pragma unroll
            for (int jj = 0; jj < 4; ++jj) {
                int gj = j0 + ty * 4 + jj;
                if (gj < 512) F[(size_t)gi * 512 + gj] -= acc[ii][jj];
            }
        }
    }
}

// ---------------- fp64 full-square-factor LL^T solve (precompute/init) ----------------
__global__ __launch_bounds__(256) void k_solve_d(
    const double* __restrict__ F,
    const float* __restrict__ rhs32,
    double* __restrict__ o1, double* __restrict__ o2,
    float* __restrict__ o1f, float* __restrict__ o2f,
    int mode)
{
    int b = blockIdx.x;
    int tid = threadIdx.x;
    __shared__ double w[512];
    __shared__ double Ft[64 * 65];
    __shared__ double red[256];
    if (rhs32) {
        w[tid] = (double)rhs32[(size_t)b * 512 + tid];
        w[tid + 256] = (double)rhs32[(size_t)b * 512 + tid + 256];
    } else {
        w[tid] = (tid == b) ? 1.0 : 0.0;
        w[tid + 256] = (tid + 256 == b) ? 1.0 : 0.0;
    }
    for (int blk = 0; blk < 8; ++blk) {
        int c0 = blk * 64;
        int r = tid & 63, q = tid >> 6;
        double acc = 0.0;
        for (int jt = 0; jt < blk; ++jt) {
            __syncthreads();
#pragma unroll
            for (int l = 0; l < 16; ++l) {
                int idx = tid + 256 * l;
                int rr = idx >> 6, cc = idx & 63;
                Ft[rr * 65 + cc] = F[(size_t)(c0 + rr) * 512 + jt * 64 + cc];
            }
            __syncthreads();
#pragma unroll
            for (int jj = 0; jj < 16; ++jj) {
                int j = q * 16 + jj;
                acc += Ft[r * 65 + j] * w[jt * 64 + j];
            }
        }
        red[tid] = acc;
        __syncthreads();
#pragma unroll
        for (int l = 0; l < 16; ++l) {
            int idx = tid + 256 * l;
            int rr = idx >> 6, cc = idx & 63;
            Ft[rr * 65 + cc] = F[(size_t)(c0 + rr) * 512 + c0 + cc];
        }
        __syncthreads();
        if (tid < 64) {
            int i = tid;
            double a = w[c0 + i] - (red[i] + red[i + 64] + red[i + 128] + red[i + 192]);
            double rd = 1.0 / Ft[i * 65 + i];
#pragma unroll
            for (int j = 0; j < 64; ++j) {
                double wj = __shfl(a, j) * __shfl(rd, j);
                if (i == j) w[c0 + i] = wj;
                if (i > j) a -= Ft[i * 65 + j] * wj;
            }
        }
        __syncthreads();
    }
    for (int blk = 7; blk >= 0; --blk) {
        int c0 = blk * 64;
        __syncthreads();
#pragma unroll
        for (int l = 0; l < 16; ++l) {
            int idx = tid + 256 * l;
            int rr = idx >> 6, cc = idx & 63;
            Ft[rr * 65 + cc] = F[(size_t)(c0 + rr) * 512 + c0 + cc];
        }
        __syncthreads();
        if (tid < 64) {
            int i = tid;
            double a = w[c0 + i];
            double rd = 1.0 / Ft[i * 65 + i];
#pragma unroll
            for (int j = 63; j >= 0; --j) {
                double wj = __shfl(a, j) * __shfl(rd, j);
                if (i == j) w[c0 + i] = wj;
                if (i < j) a -= Ft[j * 65 + i] * wj;
            }
        }
        __syncthreads();
        if (c0 > 0) {
            for (int base = 0; base < c0; base += 256) {
                int col = base + tid;
                if (col < c0) {
                    double s = 0.0;
#pragma unroll
                    for (int i2 = 0; i2 < 64; ++i2)
                        s += F[(size_t)(c0 + i2) * 512 + col] * w[c0 + i2];
                    w[col] -= s;
                }
            }
        }
    }
    __syncthreads();
#pragma unroll
    for (int l = 0; l < 2; ++l) {
        int i = tid + l * 256;
        double wv = w[i];
        size_t gi = (size_t)b * 512 + i;
        if (mode == 0) {
            o1[gi] = wv;
            o1f[gi] = (float)wv;
        } else {
            o1[gi] = -wv;
            o2[gi] = wv;
            o1f[gi] = (float)(-wv);
            o2f[gi] = (float)wv;
        }
    }
}

// ---------------- packed fp32-factor triangular solve (512 threads) ----------------
__device__ void trsv_packed(const float* __restrict__ Lb, const double* __restrict__ rdgAll,
                            double* __restrict__ wv, double* __restrict__ red, int tid)
{
    for (int j = 0; j < 16; ++j) {
        int c0 = j * 32;
        int i = tid >> 4, k = tid & 15;
        double a = 0.0;
        if (k < j) {
            const float* tp = Lb + tile_off(j, k) + i * 32;
            const double* wp = wv + k * 32;
#pragma unroll 8
            for (int m = 0; m < 32; ++m) a += (double)tp[m] * wp[m];
        }
        red[tid] = a;
        __syncthreads();
        if (tid < 32) {
            int i2 = tid;
            double s = 0.0;
#pragma unroll
            for (int k2 = 0; k2 < 16; ++k2) s += red[i2 * 16 + k2];
            double aa = wv[c0 + i2] - s;
            double rdgv = rdgAll[c0 + i2];
            const float* tp = Lb + tile_off_diag(j);
            int basei = (i2 * (i2 + 1)) >> 1;
            float lrow[32];
#pragma unroll
            for (int m = 0; m < 32; ++m) lrow[m] = (m < i2) ? tp[basei + m] : 0.f;
#pragma unroll
            for (int m = 0; m < 32; ++m) {
                double xm = __shfl(aa * rdgv, m);
                if (i2 == m) wv[c0 + i2] = xm;
                if (i2 > m) aa -= (double)lrow[m] * xm;
            }
        }
        __syncthreads();
    }
    for (int j = 15; j >= 0; --j) {
        int c0 = j * 32;
        if (tid < 32) {
            int i2 = tid;
            double aa = wv[c0 + i2];
            double rdgv = rdgAll[c0 + i2];
            const float* tp = Lb + tile_off_diag(j);
            float lcol[32];
#pragma unroll
            for (int m = 0; m < 32; ++m)
                lcol[m] = (m > i2) ? tp[((m * (m + 1)) >> 1) + i2] : 0.f;
#pragma unroll
            for (int m = 31; m >= 0; --m) {
                double xm = __shfl(aa * rdgv, m);
                if (i2 == m) wv[c0 + i2] = xm;
                if (i2 < m) aa -= (double)lcol[m] * xm;
            }
        }
        __syncthreads();
        if (j > 0) {
            int k = tid >> 5, m = tid & 31;
            if (k < j) {
                const float* tp = Lb + tile_off(j, k) + m;
                double sacc = 0.0;
#pragma unroll 8
                for (int i3 = 0; i3 < 32; ++i3) sacc += (double)tp[i3 * 32] * wv[c0 + i3];
                wv[k * 32 + m] -= sacc;
            }
            __syncthreads();
        }
    }
}

__device__ void refine_once(const double* __restrict__ S0d, const double* __restrict__ dvecS,
                            const double* __restrict__ rhsL, double* __restrict__ wv,
                            double* __restrict__ tmpS, double* __restrict__ red,
                            const float* __restrict__ Lb, const double* __restrict__ rdgAll,
                            int tid)
{
    double a = 0.0;
    const double* sp = S0d + tid;
    for (int c = 0; c < 512; ++c) a += sp[(size_t)c * 512] * wv[c];
    double r = rhsL[tid] - a - dvecS[tid] * wv[tid];
    __syncthreads();
    tmpS[tid] = r;
    __syncthreads();
    trsv_packed(Lb, rdgAll, tmpS, red, tid);
    wv[tid] += tmpS[tid];
    __syncthreads();
}

// ---------------- persistent fused per-iteration kernel (MFMA-f64 or VALU SYRK) ----------
__global__ __launch_bounds__(512) void k_fused(
    const double* __restrict__ S0d,
    float* __restrict__ F0,
    const double* __restrict__ ss, const double* __restrict__ zs,
    const float* __restrict__ hvf,
    const double* __restrict__ mu, const double* __restrict__ szs,
    float* __restrict__ dzv, float* __restrict__ dsv,
    const int* __restrict__ mfok)
{
    const int tid = threadIdx.x;
    float* Lb = F0 + (size_t)blockIdx.x * FACF;
    const int useM = mfok[0];        // 0 = VALU; 1..4 = MFMA with D-layout variant

    __shared__ double pool[9376];
    __shared__ double Dl[32 * 33];
    __shared__ double rdgS[32];
    __shared__ double rdgAll[512];
    __shared__ double wv[512], rhsL[512], dvecS[512], tmpS[512], redS[512];
    double* As = pool;
    double* Bs = pool + 32 * PITCH_AS;
    double* W  = pool;

    const int tx = tid & 63, ty = tid >> 6;
    const int lane = tid & 63, wid = tid >> 6;
    const int aoff = lane & 15, koff = lane >> 4;

    for (int b = blockIdx.x; b < 128; b += gridDim.x) {
        const size_t gb = (size_t)b * 512;
        __syncthreads();

        // ===== left-looking Cholesky, fp64 arithmetic, packed fp32 store =====
        for (int j = 0; j < 16; ++j) {
            const int c0 = j * 32;
            for (int rbase = c0; rbase < 512; rbase += 256) {
                const int rows = (512 - rbase < 256) ? (512 - rbase) : 256;

                if (useM) {
                    // ---------- MFMA-f64 variant (R7-proven: LDS-staged A and B) ----------
                    const int ntiles = (rows >> 4) << 1;
                    d4 uacc[4];
#pragma unroll
                    for (int tt = 0; tt < 4; ++tt) uacc[tt] = (d4){0.0, 0.0, 0.0, 0.0};
                    for (int k = 0; k < j; ++k) {
                        __syncthreads();
                        {
                            int rl0 = tid >> 3;
                            int kq = (tid & 7) * 4;
                            for (int rr = rl0; rr < rows; rr += 64) {
                                int gr = rbase + rr;
                                const float* tp = Lb + tile_off(gr >> 5, k) + (gr & 31) * 32 + kq;
                                float4 f4 = *(const float4*)tp;
                                As[(kq + 0) * PITCH_AS + rr] = (double)f4.x;
                                As[(kq + 1) * PITCH_AS + rr] = (double)f4.y;
                                As[(kq + 2) * PITCH_AS + rr] = (double)f4.z;
                                As[(kq + 3) * PITCH_AS + rr] = (double)f4.w;
                            }
                        }
                        {
                            const float* tp = Lb + tile_off(j, k);
#pragma unroll
                            for (int l = 0; l < 2; ++l) {
                                int idx = tid + 512 * l;
                                int c = idx >> 5, kk = idx & 31;
                                Bs[kk * 36 + c] = (double)tp[c * 32 + kk];
                            }
                        }
                        __syncthreads();
#pragma unroll
                        for (int tt = 0; tt < 4; ++tt) {
                            int t = wid + (tt << 3);
                            if (t < ntiles) {
                                int s16 = (t >> 1) << 4, hcol = (t & 1) << 4;
                                d4 uv = uacc[tt];
#pragma unroll
                                for (int k4 = 0; k4 < 8; ++k4) {
                                    double av = As[(k4 * 4 + koff) * PITCH_AS + s16 + aoff];
                                    double bv = Bs[(k4 * 4 + koff) * 36 + hcol + aoff];
                                    uv = __builtin_amdgcn_mfma_f64_16x16x4f64(av, bv, uv,
                                                                              0, 0, 0);
                                }
                                uacc[tt] = uv;
                            }
                        }
                    }
                    __syncthreads();
                    // dump U -> W via the empirically-selected D-layout variant
#pragma unroll
                    for (int tt = 0; tt < 4; ++tt) {
                        int t = wid + (tt << 3);
                        if (t < ntiles) {
                            int s16 = (t >> 1) << 4, hcol = (t & 1) << 4;
#pragma unroll
                            for (int r = 0; r < 4; ++r) {
                                int li, lj;
                                if (useM == 1)      { li = (koff << 2) + r; lj = aoff; }
                                else if (useM == 2) { li = koff + (r << 2); lj = aoff; }
                                else if (useM == 3) { li = aoff; lj = (koff << 2) + r; }
                                else                { li = aoff; lj = koff + (r << 2); }
                                W[(s16 + li) * 33 + hcol + lj] = uacc[tt][r];
                            }
                        }
                    }
                    __syncthreads();
                    // W = S0 (+ s/z diag) - U  (S0 symmetric -> coalesced column reads)
#pragma unroll
                    for (int v = 0; v < 4; ++v) {
                        int cg = c0 + 4 * ty + v;
                        const double* srow = S0d + (size_t)cg * 512 + rbase + tx;
#pragma unroll
                        for (int uu = 0; uu < 4; ++uu) {
                            int rl = tx + 64 * uu;
                            if (rl < rows) {
                                double sv = srow[64 * uu];
                                int rg = rbase + rl;
                                if (rbase == c0 && rg == cg) sv += ss[gb + rg] / zs[gb + rg];
                                W[rl * 33 + 4 * ty + v] = sv - W[rl * 33 + 4 * ty + v];
                            }
                        }
                    }
                } else {
                    // ---------- VALU variant (R4-proven) ----------
                    double acc[4][4];
#pragma unroll
                    for (int v = 0; v < 4; ++v) {
                        int cg = c0 + 4 * ty + v;
                        const double* srow = S0d + (size_t)cg * 512 + rbase + tx;
#pragma unroll
                        for (int u = 0; u < 4; ++u) {
                            int rl = tx + 64 * u;
                            acc[u][v] = (rl < rows) ? srow[64 * u] : 0.0;
                        }
                    }
                    if (rbase == c0) {
#pragma unroll
                        for (int u = 0; u < 4; ++u) {
                            int rg = rbase + tx + 64 * u;
#pragma unroll
                            for (int v = 0; v < 4; ++v) {
                                if (rg == c0 + 4 * ty + v) acc[u][v] += ss[gb + rg] / zs[gb + rg];
                            }
                        }
                    }
                    for (int k = 0; k < j; ++k) {
                        __syncthreads();
                        {
                            int rl0 = tid >> 3;
                            int kq = (tid & 7) * 4;
                            for (int rr = rl0; rr < rows; rr += 64) {
                                int gr = rbase + rr;
                                const float* tp = Lb + tile_off(gr >> 5, k) + (gr & 31) * 32 + kq;
                                float4 f4 = *(const float4*)tp;
                                As[(kq + 0) * PITCH_AS + rr] = (double)f4.x;
                                As[(kq + 1) * PITCH_AS + rr] = (double)f4.y;
                                As[(kq + 2) * PITCH_AS + rr] = (double)f4.z;
                                As[(kq + 3) * PITCH_AS + rr] = (double)f4.w;
                            }
                        }
                        {
                            const float* tp = Lb + tile_off(j, k);
#pragma unroll
                            for (int l = 0; l < 2; ++l) {
                                int idx = tid + 512 * l;
                                int c = idx >> 5, kk = idx & 31;
                                Bs[kk * 36 + c] = (double)tp[c * 32 + kk];
                            }
                        }
                        __syncthreads();
#pragma unroll 8
                        for (int kk = 0; kk < 32; ++kk) {
                            double a4[4], b4[4];
#pragma unroll
                            for (int u = 0; u < 4; ++u) a4[u] = As[kk * PITCH_AS + tx + 64 * u];
#pragma unroll
                            for (int v = 0; v < 4; ++v) b4[v] = Bs[kk * 36 + 4 * ty + v];
#pragma unroll
                            for (int u = 0; u < 4; ++u)
#pragma unroll
                                for (int v = 0; v < 4; ++v)
                                    acc[u][v] -= a4[u] * b4[v];
                        }
                    }
                    __syncthreads();
#pragma unroll
                    for (int u = 0; u < 4; ++u) {
                        int rl = tx + 64 * u;
                        if (rl < rows) {
#pragma unroll
                            for (int v = 0; v < 4; ++v)
                                W[rl * 33 + 4 * ty + v] = acc[u][v];
                        }
                    }
                }
                __syncthreads();

                // ---------- shared: diag factor + panel TRSM + packed fp32 store ----------
                int trsm0 = 0;
                if (rbase == c0) {
                    trsm0 = 32;
                    if (tid < 32) {
                        int i = tid;
                        double d[32];
#pragma unroll
                        for (int m2 = 0; m2 < 32; ++m2) d[m2] = W[i * 33 + m2];
#pragma unroll
                        for (int m2 = 0; m2 < 32; ++m2) {
                            double djj = __shfl(d[m2], m2);
                            djj = (djj > 1e-30) ? djj : 1e-30;
                            double sj = sqrt(djj);
                            double inv = 1.0 / sj;
                            if (i == m2) { d[m2] = sj; rdgS[m2] = inv; rdgAll[c0 + m2] = inv; }
                            if (i > m2) d[m2] *= inv;
                            double lij = d[m2];
#pragma unroll
                            for (int t2 = m2 + 1; t2 < 32; ++t2) {
                                double ltj = __shfl(d[m2], t2);
                                if (i >= t2) d[t2] -= lij * ltj;
                            }
                        }
                        float* tp = Lb + tile_off_diag(j);
                        int basei = (i * (i + 1)) >> 1;
#pragma unroll
                        for (int m2 = 0; m2 < 32; ++m2) {
                            if (m2 <= i) { Dl[i * 33 + m2] = d[m2]; tp[basei + m2] = (float)d[m2]; }
                        }
                    }
                    __syncthreads();
                }
                {
                    int nr = rows - trsm0;
                    if (tid < nr) {
                        int rl = trsm0 + tid;
                        int gr = rbase + rl;
                        double x[32];
#pragma unroll
                        for (int m2 = 0; m2 < 32; ++m2) x[m2] = W[rl * 33 + m2];
#pragma unroll
                        for (int m2 = 0; m2 < 32; ++m2) {
                            double xm = x[m2] * rdgS[m2];
                            x[m2] = xm;
#pragma unroll
                            for (int t2 = m2 + 1; t2 < 32; ++t2) x[t2] -= xm * Dl[t2 * 33 + m2];
                        }
                        float* tp = Lb + tile_off(gr >> 5, j) + (gr & 31) * 32;
#pragma unroll
                        for (int m2 = 0; m2 < 32; ++m2) tp[m2] = (float)x[m2];
                    }
                }
                __syncthreads();
            }
        }

        // ===== affine solve =====
        double z_t = zs[gb + tid], s_t = ss[gb + tid];
        double dv = s_t / z_t;
        dvecS[tid] = dv;
        double r1 = (double)hvf[gb + tid];
        wv[tid] = r1;
        rhsL[tid] = r1;
        __syncthreads();
        trsv_packed(Lb, rdgAll, wv, redS, tid);
        refine_once(S0d, dvecS, rhsL, wv, tmpS, redS, Lb, rdgAll, tid);

        double dza_t = -wv[tid];
        double dsa_t = -(z_t + dza_t) * dv;
        __syncthreads();

        // ===== alpha / sigma / corrector rhs =====
        double az = (dza_t < 0.0) ? (-z_t / dza_t) : BIGD;
        double as = (dsa_t < 0.0) ? (-s_t / dsa_t) : BIGD;
        redS[tid] = fmin(az, as);
        __syncthreads();
        for (int s2 = 256; s2 > 0; s2 >>= 1) {
            if (tid < s2) redS[tid] = fmin(redS[tid], redS[tid + s2]);
            __syncthreads();
        }
        double alpha = fmin(redS[0], 1.0);
        __syncthreads();
        redS[tid] = (s_t + alpha * dsa_t) * (z_t + alpha * dza_t);
        __syncthreads();
        for (int s2 = 256; s2 > 0; s2 >>= 1) {
            if (tid < s2) redS[tid] += redS[tid + s2];
            __syncthreads();
        }
        double d2 = redS[0];
        __syncthreads();
        double ratio = d2 / szs[b];
        double sig = ratio * ratio * ratio;
        double coef = -mu[b] * sig;
        double num = coef + dsa_t * dza_t;
        double rsc_t = num / s_t;
        wv[tid] = num / z_t;
        rhsL[tid] = wv[tid];
        __syncthreads();

        // ===== corrector solve =====
        trsv_packed(Lb, rdgAll, wv, redS, tid);
        refine_once(S0d, dvecS, rhsL, wv, tmpS, redS, Lb, rdgAll, tid);

        double dz = dza_t - wv[tid];
        double ds = -(z_t + rsc_t + dz) * dv;
        dzv[gb + tid] = (float)dz;
        dsv[gb + tid] = (float)ds;
    }
}

// ---------------- per-batch residual stats (fp32 residual inputs) ----------------
__global__ __launch_bounds__(256) void k_stats_d(
    const float* __restrict__ rx, const float* __restrict__ rz,
    const double* __restrict__ ssv, const double* __restrict__ zsv,
    double* resid, double* mu, double* szsum)
{
    int b = blockIdx.x, tid = threadIdx.x;
    __shared__ double red[256];
    double s1 = 0, s2 = 0, s3 = 0;
#pragma unroll
    for (int l = 0; l < 2; ++l) {
        size_t gi = (size_t)b * 512 + tid + l * 256;
        double vx = (double)rx[gi]; s1 += vx * vx;
        double vz = (double)rz[gi]; s2 += vz * vz;
        s3 += ssv[gi] * zsv[gi];
    }
    double t1 = blk_reduce_sum_d(s1, red);
    double t2 = blk_reduce_sum_d(s2, red);
    double t3 = blk_reduce_sum_d(s3, red);
    if (tid == 0) {
        resid[b] = sqrt(t2) + sqrt(t1) + fabs(t3);
        mu[b] = fabs(t3) / 512.0;
        szsum[b] = t3;
    }
}

__global__ void k_best_d(const double* __restrict__ resid, double* bsum, double* flag) {
    __shared__ double red[128];
    int tid = threadIdx.x;
    red[tid] = resid[tid];
    __syncthreads();
    for (int s = 64; s > 0; s >>= 1) {
        if (tid < s) red[tid] += red[tid + s];
        __syncthreads();
    }
    if (tid == 0) {
        double rs = red[0];
        if (rs < bsum[0]) { bsum[0] = rs; flag[0] = 1.0; }
        else flag[0] = 0.0;
    }
}

__global__ void k_bestcopy_d(const double* __restrict__ flag, const double* __restrict__ xs,
                             float* __restrict__ bx) {
    if (flag && flag[0] == 0.0) return;
    int i0 = blockIdx.x * 1024 + threadIdx.x;
#pragma unroll
    for (int l = 0; l < 4; ++l) bx[i0 + l * 256] = (float)xs[i0 + l * 256];
}

// ---------------- final step (fp64 master + fp32 shadows) ----------------
__global__ __launch_bounds__(256) void k_final_d(
    double* __restrict__ xs, double* __restrict__ ssv, double* __restrict__ zsv,
    const float* __restrict__ dxf, const float* __restrict__ dsf, const float* __restrict__ dzf,
    float* __restrict__ xs32, float* __restrict__ ss32, float* __restrict__ zs32)
{
    int b = blockIdx.x, tid = threadIdx.x;
    __shared__ double red[256];
    double m = BIGD;
#pragma unroll
    for (int l = 0; l < 2; ++l) {
        size_t gi = (size_t)b * 512 + tid + l * 256;
        double z = zsv[gi], dz = (double)dzf[gi];
        double az = (dz < 0.0) ? (-z / dz) : BIGD;
        double s = ssv[gi], ds = (double)dsf[gi];
        double as = (ds < 0.0) ? (-s / ds) : BIGD;
        m = fmin(m, fmin(az, as));
    }
    double am = blk_reduce_min_d(m, red);
    double alpha = fmin(0.999 * am, 1.0);
#pragma unroll
    for (int l = 0; l < 2; ++l) {
        size_t gi = (size_t)b * 512 + tid + l * 256;
        double nx = xs[gi] + alpha * (double)dxf[gi];
        double ns = ssv[gi] + alpha * (double)dsf[gi];
        double nz = zsv[gi] + alpha * (double)dzf[gi];
        xs[gi] = nx; ssv[gi] = ns; zsv[gi] = nz;
        xs32[gi] = (float)nx; ss32[gi] = (float)ns; zs32[gi] = (float)nz;
    }
}

// ---------------- initial interior shift (+ shadow refresh) ----------------
__global__ __launch_bounds__(256) void k_shift_d(double* __restrict__ ssv, double* __restrict__ zsv,
                                                 float* __restrict__ ss32, float* __restrict__ zs32)
{
    int b = blockIdx.x, tid = threadIdx.x;
    __shared__ double red[256];
    double m = BIGD;
#pragma unroll
    for (int l = 0; l < 2; ++l) m = fmin(m, ssv[(size_t)b * 512 + tid + l * 256]);
    double smin = blk_reduce_min_d(m, red);
    if (smin < 0.0) {
#pragma unroll
        for (int l = 0; l < 2; ++l) ssv[(size_t)b * 512 + tid + l * 256] += 1.0 - smin;
    }
    m = BIGD;
#pragma unroll
    for (int l = 0; l < 2; ++l) m = fmin(m, zsv[(size_t)b * 512 + tid + l * 256]);
    double zmin = blk_reduce_min_d(m, red);
    if (zmin < 0.0) {
#pragma unroll
        for (int l = 0; l < 2; ++l) zsv[(size_t)b * 512 + tid + l * 256] += 1.0 - zmin;
    }
#pragma unroll
    for (int l = 0; l < 2; ++l) {
        size_t gi = (size_t)b * 512 + tid + l * 256;
        ss32[gi] = (float)ssv[gi];
        zs32[gi] = (float)zsv[gi];
    }
}

extern "C" void kernel_launch(void* const* d_in, const int* in_sizes, int n_in,
                              void* d_out, int out_size, void* d_ws, size_t ws_size,
                              hipStream_t stream)
{
    (void)in_sizes; (void)n_in; (void)out_size;
    const float* xin = (const float*)d_in[0];
    const float* Mi  = (const float*)d_in[1];
    const float* Li  = (const float*)d_in[2];
    const float* Gin = (const float*)d_in[3];
    const float* s0  = (const float*)d_in[4];
    const float* z0  = (const float*)d_in[5];
    float* outp = (float*)d_out;

    const size_t N2 = N2C;
    double* base = (double*)d_ws;
    size_t off = 0;
    auto A = [&](size_t n) { double* p = base + off; off += n; return p; };
    // persistent fp64
    double* S0d  = A(N2);
    double* h    = A(512);
    double* resid = A(128); double* mu = A(128); double* szs = A(128);
    double* bsum = A(8); double* flag = A(8);
    double* mfokd = A(8);
    int* mfok = (int*)mfokd;
    double* xs = A(65536); double* ss = A(65536); double* zs = A(65536);
    // persistent fp32 (allocated in dbl units)
    float* Qf   = (float*)A(131072);
    float* GTf  = (float*)A(131072);
    float* Qif  = (float*)A(131072);
    float* h32  = (float*)A(256);
    float* rxf  = (float*)A(32768);
    float* rzf  = (float*)A(32768);
    float* hvf  = (float*)A(32768);
    float* t1f  = (float*)A(32768);
    float* dzvf = (float*)A(32768);
    float* dsvf = (float*)A(32768);
    float* xs32 = (float*)A(32768);
    float* ss32 = (float*)A(32768);
    float* zs32 = (float*)A(32768);
    float* dxf = hvf;   // alias: hv dead after fused
    float* t2f = t1f;   // alias: t1 dead after hv GEMM

    double* slab = base + off;
    size_t avail = (ws_size / 8 > off) ? (ws_size / 8 - off) : 0;
    int C = (int)(avail / (FACF / 2));   // FACF floats = FACF/2 dbl per batch
    if (C > 128) C = 128;
    if (C < 1) C = 1;
    float* F0 = (float*)slab;
    // precompute fp64 overlays in slab (dead once iterations start)
    double* Lm64  = slab;
    double* LmT64 = slab + 1 * N2;
    double* Q64   = slab + 2 * N2;
    double* Lq    = slab + 3 * N2;
    double* Qi64  = slab + 4 * N2;
    double* G64   = slab + 5 * N2;
    double* GT64  = slab + 6 * N2;
    double* X64   = slab + 7 * N2;
    double* SfI   = slab + 8 * N2;

    dim3 t256(256), t512(512);
    const float* NPf = nullptr;

    // -------- precompute --------
    k_mfmatest<<<1, 64, 0, stream>>>(mfok);
    k_lm<<<1024, t256, 0, stream>>>(Mi, Li, Lm64, 262144);
    k_transpose_d<<<256, t256, 0, stream>>>(Lm64, LmT64);
    k_bgemm_d<<<64, t256, 0, stream>>>(Lm64, LmT64, Q64, 1.0, 1e-4);
    k_cast32v<<<1024, t256, 0, stream>>>(Q64, Qf, 262144);
    k_copyadd_d<<<1024, t256, 0, stream>>>(Q64, Lq, 0.0, 262144);
    for (int kp = 0; kp < 16; ++kp) {
        k_cpanel_d<<<1, t512, 0, stream>>>(Lq, kp);
        int Tr = 480 - 32 * kp;
        if (Tr > 0) {
            int T = (Tr + 63) >> 6;
            k_syrk_d<<<T * (T + 1) / 2, t256, 0, stream>>>(Lq, kp);
        }
    }
    k_solve_d<<<512, t256, 0, stream>>>(Lq, NPf, Qi64, nullptr, Qif, nullptr, 0);
    k_cast<<<1024, t256, 0, stream>>>(Gin, G64, 262144);
    k_transpose_d<<<256, t256, 0, stream>>>(G64, GT64);
    k_transpose32<<<256, t256, 0, stream>>>(Gin, GTf);
    k_bgemm_d<<<64, t256, 0, stream>>>(Qi64, GT64, X64, 1.0, 0.0);
    k_bgemm_d<<<64, t256, 0, stream>>>(G64, X64, S0d, 1.0, 0.0);
    k_copyadd_d<<<1024, t256, 0, stream>>>(S0d, SfI, 1.0, 262144);
    for (int kp = 0; kp < 16; ++kp) {
        k_cpanel_d<<<1, t512, 0, stream>>>(SfI, kp);
        int Tr = 480 - 32 * kp;
        if (Tr > 0) {
            int T = (Tr + 63) >> 6;
            k_syrk_d<<<T * (T + 1) / 2, t256, 0, stream>>>(SfI, kp);
        }
    }
    k_h_d<<<8, t256, 0, stream>>>(Gin, s0, z0, h);
    k_cast32v<<<2, t256, 0, stream>>>(h, h32, 512);
    k_initbsum<<<1, 64, 0, stream>>>(bsum);

    // -------- initial point --------
    k_gemm32<<<32, t256, 0, stream>>>(xin, Qif, NPf, NPf, t1f, NPf, NPf, NPf, 0.f, 1.f);
    k_gemm32<<<32, t256, 0, stream>>>(t1f, GTf, NPf, NPf, hvf, NPf, NPf, h32, 1.f, 1.f);
    k_solve_d<<<128, t256, 0, stream>>>(SfI, hvf, zs, ss, zs32, ss32, 1);
    k_gemm32<<<32, t256, 0, stream>>>(zs32, Gin, NPf, NPf, t1f, xin, NPf, NPf, 0.f, 1.f);
    k_gemm32<<<32, t256, 0, stream>>>(t1f, Qif, NPf, NPf, xs32, NPf, NPf, NPf, 0.f, -1.f);
    k_cast<<<256, t256, 0, stream>>>(xs32, xs, 65536);
    k_shift_d<<<128, t256, 0, stream>>>(ss, zs, ss32, zs32);
    k_bestcopy_d<<<64, t256, 0, stream>>>(nullptr, xs, outp);

    // -------- 20 PDIPM iterations --------
    int fgrid = (C < 128) ? C : 128;
    for (int it = 0; it < 20; ++it) {
        k_gemm32<<<32, t256, 0, stream>>>(xs32, Qf, zs32, Gin, rxf, xin, NPf, NPf, 0.f, 1.f);
        k_gemm32<<<32, t256, 0, stream>>>(xs32, GTf, NPf, NPf, rzf, ss32, NPf, h32, -1.f, 1.f);
        k_stats_d<<<128, t256, 0, stream>>>(rxf, rzf, ss, zs, resid, mu, szs);
        k_best_d<<<1, 128, 0, stream>>>(resid, bsum, flag);
        k_bestcopy_d<<<64, t256, 0, stream>>>(flag, xs, outp);
        k_gemm32<<<32, t256, 0, stream>>>(rxf, Qif, NPf, NPf, t1f, NPf, NPf, NPf, 0.f, 1.f);
        k_gemm32<<<32, t256, 0, stream>>>(t1f, GTf, NPf, NPf, hvf, ss32, rzf, NPf, 0.f, 1.f);
        k_fused<<<fgrid, t512, 0, stream>>>(S0d, F0, ss, zs, hvf, mu, szs, dzvf, dsvf, mfok);
        k_gemm32<<<32, t256, 0, stream>>>(dzvf, Gin, NPf, NPf, t2f, rxf, NPf, NPf, 0.f, 1.f);
        k_gemm32<<<32, t256, 0, stream>>>(t2f, Qif, NPf, NPf, dxf, NPf, NPf, NPf, 0.f, -1.f);
        k_final_d<<<128, t256, 0, stream>>>(xs, ss, zs, dxf, dsvf, dzvf, xs32, ss32, zs32);
    }
}